// Round 15
// baseline (811.822 us; speedup 1.0000x reference)
//
#include <hip/hip_runtime.h>
#include <hip/hip_bf16.h>

#define NN 100000
#define MP 100096  // 782 * 128, padded row count for all [M,*] buffers we own

typedef unsigned short u16;
typedef __attribute__((ext_vector_type(8))) short bf16x8;
typedef __attribute__((ext_vector_type(4))) float f32x4;

static inline size_t align_up(size_t x, size_t a) { return (x + a - 1) & ~(a - 1); }

__device__ inline u16 f2b(float f) {  // RNE f32 -> bf16 (finite inputs)
    unsigned u = __float_as_uint(f);
    return (u16)((u + 0x7FFF + ((u >> 16) & 1)) >> 16);
}
__device__ inline float b2f(u16 u) { return __uint_as_float(((unsigned)u) << 16); }

// ---------------- CSR build ----------------

__global__ __launch_bounds__(256) void deg_count_kernel(const int* __restrict__ dst,
                                                        int* __restrict__ deg, int E) {
    int t = blockIdx.x * 256 + threadIdx.x;
    if (t < E) atomicAdd(&deg[dst[t]], 1);
}

// phase1 + fused dinv: per-block sums -> partials[b]; dinv[i] = rsqrt(deg+1)
__global__ __launch_bounds__(256) void scan_phase1(const int* __restrict__ deg,
                                                   int* __restrict__ partials,
                                                   float* __restrict__ dinv, int n4) {
    __shared__ int red[256];
    const int t = threadIdx.x;
    const int g = blockIdx.x * 256 + t;
    int4 v = make_int4(0, 0, 0, 0);
    if (g < n4) {
        v = ((const int4*)deg)[g];
        float4 dv;
        dv.x = rsqrtf((float)v.x + 1.0f);
        dv.y = rsqrtf((float)v.y + 1.0f);
        dv.z = rsqrtf((float)v.z + 1.0f);
        dv.w = rsqrtf((float)v.w + 1.0f);
        ((float4*)dinv)[g] = dv;
    }
    red[t] = v.x + v.y + v.z + v.w;
    __syncthreads();
    #pragma unroll
    for (int d = 128; d; d >>= 1) {
        if (t < d) red[t] += red[t + d];
        __syncthreads();
    }
    if (t == 0) partials[blockIdx.x] = red[0];
}

__global__ __launch_bounds__(128) void scan_phase2(int* __restrict__ partials,
                                                   int* __restrict__ rowptr, int nb, int n) {
    __shared__ int ps[128];
    const int t = threadIdx.x;
    int v = (t < nb) ? partials[t] : 0;
    ps[t] = v;
    __syncthreads();
    #pragma unroll
    for (int d = 1; d < 128; d <<= 1) {
        int u = (t >= d) ? ps[t - d] : 0;
        __syncthreads();
        ps[t] += u;
        __syncthreads();
    }
    if (t < nb) partials[t] = ps[t] - v;   // exclusive prefix
    if (t == nb - 1) rowptr[n] = ps[t];    // total
}

__global__ __launch_bounds__(256) void scan_phase3(const int* __restrict__ deg,
                                                   const int* __restrict__ partials,
                                                   int* __restrict__ rowptr, int n4) {
    __shared__ int ts[256];
    const int t = threadIdx.x;
    const int g = blockIdx.x * 256 + t;
    int4 v = make_int4(0, 0, 0, 0);
    if (g < n4) v = ((const int4*)deg)[g];
    const int s0 = v.x, s1 = s0 + v.y, s2 = s1 + v.z, s3 = s2 + v.w;
    ts[t] = s3;
    __syncthreads();
    #pragma unroll
    for (int d = 1; d < 256; d <<= 1) {
        int u = (t >= d) ? ts[t - d] : 0;
        __syncthreads();
        ts[t] += u;
        __syncthreads();
    }
    if (g < n4) {
        const int base = partials[blockIdx.x] + ts[t] - s3;
        int4 r;
        r.x = base; r.y = base + s0; r.z = base + s1; r.w = base + s2;
        ((int4*)rowptr)[g] = r;
    }
}

// scatter edges into dst-sorted order as (src, norm) 8-byte records
__global__ __launch_bounds__(256) void reorder_kernel(const int* __restrict__ src,
        const int* __restrict__ dst, const int* __restrict__ rowptr,
        int* __restrict__ cursor, const float* __restrict__ dinv,
        int2* __restrict__ erec, int E) {
    int e = blockIdx.x * 256 + threadIdx.x;
    if (e >= E) return;
    int s = src[e], d = dst[e];
    int pos = rowptr[d] + atomicAdd(&cursor[d], 1);
    erec[pos] = make_int2(s, __float_as_int(dinv[s] * dinv[d]));
}

// ---------------- all three weight transposes in one kernel ----------------
// ranges (elements): wt1 512x256 -> [0,131072), wt2 256x128 -> [131072,163840),
// wt3 128x64 -> [163840,172032)
__global__ __launch_bounds__(256) void transpose_all(const float* __restrict__ W1,
        const float* __restrict__ W2, const float* __restrict__ W3,
        u16* __restrict__ wt1, u16* __restrict__ wt2, u16* __restrict__ wt3) {
    int t = blockIdx.x * 256 + threadIdx.x;
    if (t < 131072) {
        int n = t >> 9, k = t & 511;                 // K=512, N=256
        wt1[t] = f2b(W1[(size_t)k * 256 + n]);
    } else if (t < 163840) {
        int i = t - 131072;
        int n = i >> 8, k = i & 255;                 // K=256, N=128
        wt2[i] = f2b(W2[(size_t)k * 128 + n]);
    } else if (t < 172032) {
        int i = t - 163840;
        int n = i >> 7, k = i & 127;                 // K=128, N=64
        wt3[i] = f2b(W3[(size_t)k * 64 + n]);
    }
}

// ---------------- MFMA GEMM, bf16 A (layers 2,3) ----------------
// ncols: only store output cols < ncols (layer 3 writes dense [MP][64])
__global__ __launch_bounds__(256) void gemm_mfma(const u16* __restrict__ A,
        const u16* __restrict__ BT, u16* __restrict__ C, int K, int ldc, int ncols) {
    __shared__ char lds[32768];
    char* Al = lds;
    char* Bl = lds + 16384;
    const int tid = threadIdx.x;
    const int l = tid & 63;
    const int w = tid >> 6;
    const int wm = w >> 1, wn = w & 1;
    const long bm = (long)blockIdx.x * 128;
    const long bn = (long)blockIdx.y * 128;

    f32x4 acc[4][4];
    #pragma unroll
    for (int mi = 0; mi < 4; ++mi)
        #pragma unroll
        for (int ni = 0; ni < 4; ++ni)
            acc[mi][ni] = (f32x4){0.f, 0.f, 0.f, 0.f};

    const int srow = tid >> 3;
    const int schunk = (tid & 7) << 4;

    for (int k0 = 0; k0 < K; k0 += 64) {
        __syncthreads();
        #pragma unroll
        for (int i = 0; i < 4; ++i) {
            const int row = i * 32 + srow;
            const int lb = schunk ^ ((row & 7) << 4);
            const u16* ga = A + (bm + row) * K + k0 + (lb >> 1);
            const u16* gb = BT + (bn + row) * K + k0 + (lb >> 1);
            char* la = Al + i * 4096 + tid * 16;
            char* lbp = Bl + i * 4096 + tid * 16;
            __builtin_amdgcn_global_load_lds((const __attribute__((address_space(1))) void*)ga,
                                             (__attribute__((address_space(3))) void*)la, 16, 0, 0);
            __builtin_amdgcn_global_load_lds((const __attribute__((address_space(1))) void*)gb,
                                             (__attribute__((address_space(3))) void*)lbp, 16, 0, 0);
        }
        __syncthreads();
        #pragma unroll
        for (int kk = 0; kk < 2; ++kk) {
            const int kbyte = kk * 64 + ((l >> 4) << 4);
            const int swz = (l & 7) << 4;
            bf16x8 af[4], bfr[4];
            #pragma unroll
            for (int mi = 0; mi < 4; ++mi) {
                const int row = wm * 64 + mi * 16 + (l & 15);
                af[mi] = *(const bf16x8*)(Al + row * 128 + (kbyte ^ swz));
            }
            #pragma unroll
            for (int ni = 0; ni < 4; ++ni) {
                const int row = wn * 64 + ni * 16 + (l & 15);
                bfr[ni] = *(const bf16x8*)(Bl + row * 128 + (kbyte ^ swz));
            }
            #pragma unroll
            for (int mi = 0; mi < 4; ++mi)
                #pragma unroll
                for (int ni = 0; ni < 4; ++ni)
                    acc[mi][ni] = __builtin_amdgcn_mfma_f32_16x16x32_bf16(
                        af[mi], bfr[ni], acc[mi][ni], 0, 0, 0);
        }
    }

    const long r0 = bm + wm * 64 + ((l >> 4) << 2);
    const long c0 = bn + wn * 64 + (l & 15);
    #pragma unroll
    for (int mi = 0; mi < 4; ++mi)
        #pragma unroll
        for (int r = 0; r < 4; ++r) {
            const long row = r0 + mi * 16 + r;
            #pragma unroll
            for (int ni = 0; ni < 4; ++ni) {
                const long c = c0 + ni * 16;
                if (c < ncols) C[row * ldc + c] = f2b(acc[mi][ni][r]);
            }
        }
}

// ---------------- MFMA GEMM, fp32 A fused-convert (layer 1) ----------------
__global__ __launch_bounds__(256) void gemm_mfma_f32a(const float* __restrict__ A32,
        const u16* __restrict__ BT, u16* __restrict__ C, int K, int ldc) {
    __shared__ char lds[32768];
    char* Al = lds;
    char* Bl = lds + 16384;
    const int tid = threadIdx.x;
    const int l = tid & 63;
    const int w = tid >> 6;
    const int wm = w >> 1, wn = w & 1;
    const long bm = (long)blockIdx.x * 128;
    const long bn = (long)blockIdx.y * 128;

    f32x4 acc[4][4];
    #pragma unroll
    for (int mi = 0; mi < 4; ++mi)
        #pragma unroll
        for (int ni = 0; ni < 4; ++ni)
            acc[mi][ni] = (f32x4){0.f, 0.f, 0.f, 0.f};

    const int srow = tid >> 3;          // 0..31
    const int schunk = (tid & 7) << 4;  // logical bf16 byte-in-row 0..112

    for (int k0 = 0; k0 < K; k0 += 64) {
        __syncthreads();
        #pragma unroll
        for (int i = 0; i < 4; ++i) {
            const int row = i * 32 + srow;
            const int lb = schunk ^ ((row & 7) << 4);
            const u16* gb = BT + (bn + row) * K + k0 + (lb >> 1);
            char* lbp = Bl + i * 4096 + tid * 16;
            __builtin_amdgcn_global_load_lds((const __attribute__((address_space(1))) void*)gb,
                                             (__attribute__((address_space(3))) void*)lbp, 16, 0, 0);
        }
        float4 a0[4], a1[4];
        #pragma unroll
        for (int i = 0; i < 4; ++i) {
            const int row = i * 32 + srow;
            const long ar = (bm + row < NN) ? (bm + row) : (NN - 1);  // clamp: no OOB
            const float* ga = A32 + ar * K + k0 + (schunk >> 1);
            a0[i] = *(const float4*)ga;
            a1[i] = *(const float4*)(ga + 4);
        }
        #pragma unroll
        for (int i = 0; i < 4; ++i) {
            const int row = i * 32 + srow;
            bf16x8 v;
            v[0] = (short)f2b(a0[i].x); v[1] = (short)f2b(a0[i].y);
            v[2] = (short)f2b(a0[i].z); v[3] = (short)f2b(a0[i].w);
            v[4] = (short)f2b(a1[i].x); v[5] = (short)f2b(a1[i].y);
            v[6] = (short)f2b(a1[i].z); v[7] = (short)f2b(a1[i].w);
            *(bf16x8*)(Al + row * 128 + (schunk ^ ((row & 7) << 4))) = v;
        }
        __syncthreads();
        #pragma unroll
        for (int kk = 0; kk < 2; ++kk) {
            const int kbyte = kk * 64 + ((l >> 4) << 4);
            const int swz = (l & 7) << 4;
            bf16x8 af[4], bfr[4];
            #pragma unroll
            for (int mi = 0; mi < 4; ++mi) {
                const int row = wm * 64 + mi * 16 + (l & 15);
                af[mi] = *(const bf16x8*)(Al + row * 128 + (kbyte ^ swz));
            }
            #pragma unroll
            for (int ni = 0; ni < 4; ++ni) {
                const int row = wn * 64 + ni * 16 + (l & 15);
                bfr[ni] = *(const bf16x8*)(Bl + row * 128 + (kbyte ^ swz));
            }
            #pragma unroll
            for (int mi = 0; mi < 4; ++mi)
                #pragma unroll
                for (int ni = 0; ni < 4; ++ni)
                    acc[mi][ni] = __builtin_amdgcn_mfma_f32_16x16x32_bf16(
                        af[mi], bfr[ni], acc[mi][ni], 0, 0, 0);
        }
    }

    const long r0 = bm + wm * 64 + ((l >> 4) << 2);
    const long c0 = bn + wn * 64 + (l & 15);
    #pragma unroll
    for (int mi = 0; mi < 4; ++mi)
        #pragma unroll
        for (int r = 0; r < 4; ++r) {
            const long row = r0 + mi * 16 + r;
            #pragma unroll
            for (int ni = 0; ni < 4; ++ni)
                C[row * ldc + c0 + ni * 16] = f2b(acc[mi][ni][r]);
        }
}

// ---------------- aggregation: feature-sliced gather ----------------
// Processes a 64*VEC-column slice. h/out pre-offset by the column offset;
// ldh/ldo are the FULL row strides (u16 elems). Accum order per feature
// identical to unsliced version -> bit-identical results.

template<int VEC, bool RELU>
__global__ __launch_bounds__(256) void agg_slice(const u16* __restrict__ h, int ldh,
        const int* __restrict__ rowptr, const int2* __restrict__ erec,
        const float* __restrict__ dinv, const float* __restrict__ bias,
        u16* __restrict__ out, int ldo, int N) {
    const int node = blockIdx.x * 4 + (threadIdx.x >> 6);
    if (node >= N) return;
    const int lane = threadIdx.x & 63;
    const float di = dinv[node];
    const float d2 = di * di;
    float acc[VEC];
    {
        const u16* hp = h + (size_t)node * ldh + lane * VEC;
        if constexpr (VEC == 4) {
            ushort4 v = *(const ushort4*)hp;
            float4 b = *(const float4*)(bias + lane * 4);
            acc[0] = b2f(v.x) * d2 + b.x; acc[1] = b2f(v.y) * d2 + b.y;
            acc[2] = b2f(v.z) * d2 + b.z; acc[3] = b2f(v.w) * d2 + b.w;
        } else {
            ushort2 v = *(const ushort2*)hp;
            float2 b = *(const float2*)(bias + lane * 2);
            acc[0] = b2f(v.x) * d2 + b.x; acc[1] = b2f(v.y) * d2 + b.y;
        }
    }
    const int e0 = rowptr[node], e1 = rowptr[node + 1];
    int e = e0;
    for (; e + 4 <= e1; e += 4) {
        int2 r[4];
        #pragma unroll
        for (int j = 0; j < 4; ++j) r[j] = erec[e + j];
        if constexpr (VEC == 4) {
            ushort4 v[4];
            #pragma unroll
            for (int j = 0; j < 4; ++j)
                v[j] = *(const ushort4*)(h + (size_t)r[j].x * ldh + lane * 4);
            #pragma unroll
            for (int j = 0; j < 4; ++j) {
                const float wj = __int_as_float(r[j].y);
                acc[0] += b2f(v[j].x) * wj; acc[1] += b2f(v[j].y) * wj;
                acc[2] += b2f(v[j].z) * wj; acc[3] += b2f(v[j].w) * wj;
            }
        } else {
            ushort2 v[4];
            #pragma unroll
            for (int j = 0; j < 4; ++j)
                v[j] = *(const ushort2*)(h + (size_t)r[j].x * ldh + lane * 2);
            #pragma unroll
            for (int j = 0; j < 4; ++j) {
                const float wj = __int_as_float(r[j].y);
                acc[0] += b2f(v[j].x) * wj; acc[1] += b2f(v[j].y) * wj;
            }
        }
    }
    for (; e < e1; ++e) {
        int2 r = erec[e];
        const float wgt = __int_as_float(r.y);
        const u16* sp = h + (size_t)r.x * ldh + lane * VEC;
        if constexpr (VEC == 4) {
            ushort4 v = *(const ushort4*)sp;
            acc[0] += b2f(v.x) * wgt; acc[1] += b2f(v.y) * wgt;
            acc[2] += b2f(v.z) * wgt; acc[3] += b2f(v.w) * wgt;
        } else {
            ushort2 v = *(const ushort2*)sp;
            acc[0] += b2f(v.x) * wgt; acc[1] += b2f(v.y) * wgt;
        }
    }
    u16* op = out + (size_t)node * ldo + lane * VEC;
    if constexpr (VEC == 4) {
        ushort4 r;
        r.x = f2b(RELU ? fmaxf(acc[0], 0.f) : acc[0]);
        r.y = f2b(RELU ? fmaxf(acc[1], 0.f) : acc[1]);
        r.z = f2b(RELU ? fmaxf(acc[2], 0.f) : acc[2]);
        r.w = f2b(RELU ? fmaxf(acc[3], 0.f) : acc[3]);
        *(ushort4*)op = r;
    } else {
        ushort2 r;
        r.x = f2b(RELU ? fmaxf(acc[0], 0.f) : acc[0]);
        r.y = f2b(RELU ? fmaxf(acc[1], 0.f) : acc[1]);
        *(ushort2*)op = r;
    }
}

// final layer: h is [MP][64] bf16 dense; fused log_softmax, fp32 out
__global__ __launch_bounds__(256) void agg_lsm_kernel(const u16* __restrict__ h,
        const int* __restrict__ rowptr, const int2* __restrict__ erec,
        const float* __restrict__ dinv, const float* __restrict__ bias,
        float* __restrict__ out, int N) {
    const int node = blockIdx.x * 4 + (threadIdx.x >> 6);
    if (node >= N) return;
    const int lane = threadIdx.x & 63;
    const float di = dinv[node];
    float acc = b2f(h[(size_t)node * 64 + lane]) * di * di + bias[lane];
    const int e0 = rowptr[node], e1 = rowptr[node + 1];
    int e = e0;
    for (; e + 4 <= e1; e += 4) {
        int2 r[4];
        #pragma unroll
        for (int j = 0; j < 4; ++j) r[j] = erec[e + j];
        float v[4];
        #pragma unroll
        for (int j = 0; j < 4; ++j) v[j] = b2f(h[(size_t)r[j].x * 64 + lane]);
        #pragma unroll
        for (int j = 0; j < 4; ++j) acc += v[j] * __int_as_float(r[j].y);
    }
    for (; e < e1; ++e) {
        int2 r = erec[e];
        acc += b2f(h[(size_t)r.x * 64 + lane]) * __int_as_float(r.y);
    }
    float m = acc;
    #pragma unroll
    for (int o = 32; o; o >>= 1) m = fmaxf(m, __shfl_xor(m, o, 64));
    float ex = __expf(acc - m);
    float s = ex;
    #pragma unroll
    for (int o = 32; o; o >>= 1) s += __shfl_xor(s, o, 64);
    out[(size_t)node * 64 + lane] = acc - m - __logf(s);
}

// ---------------- launch ----------------

extern "C" void kernel_launch(void* const* d_in, const int* in_sizes, int n_in,
                              void* d_out, int out_size, void* d_ws, size_t ws_size,
                              hipStream_t stream) {
    const float* x  = (const float*)d_in[0];
    const int*   ei = (const int*)d_in[1];
    const float* W1 = (const float*)d_in[2];
    const float* b1 = (const float*)d_in[3];
    const float* W2 = (const float*)d_in[4];
    const float* b2 = (const float*)d_in[5];
    const float* W3 = (const float*)d_in[6];
    const float* b3 = (const float*)d_in[7];
    const int E = in_sizes[1] / 2;
    const int* src = ei;
    const int* dst = ei + E;
    const int N = NN;
    const int N4 = N / 4;                  // 25000 (N % 4 == 0)
    const int NB = (N4 + 255) / 256;       // 98 scan blocks

    char* ws = (char*)d_ws;
    int*   deg      = (int*)ws;    ws += align_up((size_t)N * 4, 256);
    int*   cursor   = (int*)ws;    ws += align_up((size_t)N * 4, 256);
    float* dinv     = (float*)ws;  ws += align_up((size_t)N * 4, 256);
    int*   rowptr   = (int*)ws;    ws += align_up((size_t)(N + 1) * 4, 256);
    int*   partials = (int*)ws;    ws += align_up((size_t)128 * 4, 256);
    int2*  erec     = (int2*)ws;   ws += align_up((size_t)E * 8, 256);
    u16*   wt1      = (u16*)ws;    ws += align_up((size_t)256 * 512 * 2, 256);
    u16*   wt2      = (u16*)ws;    ws += align_up((size_t)128 * 256 * 2, 256);
    u16*   wt3      = (u16*)ws;    ws += align_up((size_t)128 * 128 * 2, 256);
    u16*   bufH     = (u16*)ws;    ws += (size_t)MP * 256 * 2;  // h1b; later h3b [MP][64]
    u16*   bufAct   = (u16*)ws;    ws += (size_t)MP * 256 * 2;  // act1b / act2b
    u16*   h2b      = (u16*)ws;    ws += (size_t)MP * 128 * 2;  // h2 [MP][128]
    u16*   h3b  = bufH;
    float* out  = (float*)d_out;

    // deg and cursor are contiguous (each align_up(N*4,256)): one memset
    hipMemsetAsync(deg, 0, 2 * align_up((size_t)N * 4, 256), stream);

    deg_count_kernel<<<(E + 255) / 256, 256, 0, stream>>>(dst, deg, E);
    scan_phase1<<<NB, 256, 0, stream>>>(deg, partials, dinv, N4);
    scan_phase2<<<1, 128, 0, stream>>>(partials, rowptr, NB, N);
    scan_phase3<<<NB, 256, 0, stream>>>(deg, partials, rowptr, N4);
    reorder_kernel<<<(E + 255) / 256, 256, 0, stream>>>(src, dst, rowptr, cursor, dinv, erec, E);

    transpose_all<<<(172032 + 255) / 256, 256, 0, stream>>>(W1, W2, W3, wt1, wt2, wt3);

    const int GB = MP / 128;
    const int AB = (N + 3) / 4;

    // ---- layer 1: 512 -> 256 (fused fp32->bf16 A-convert); agg in 2 column slices ----
    gemm_mfma_f32a<<<dim3(GB, 2), 256, 0, stream>>>(x, wt1, bufH, 512, 256);
    agg_slice<2, true><<<AB, 256, 0, stream>>>(bufH,       256, rowptr, erec, dinv, b1,       bufAct,       256, N);
    agg_slice<2, true><<<AB, 256, 0, stream>>>(bufH + 128, 256, rowptr, erec, dinv, b1 + 128, bufAct + 128, 256, N);

    // ---- layer 2: 256 -> 128 ----
    gemm_mfma<<<dim3(GB, 1), 256, 0, stream>>>(bufAct, wt2, h2b, 256, 128, 128);
    agg_slice<2, true><<<AB, 256, 0, stream>>>(h2b, 128, rowptr, erec, dinv, b2, bufAct, 128, N);

    // ---- layer 3: 128 -> 64 (dense [MP][64] output) ----
    gemm_mfma<<<dim3(GB, 1), 256, 0, stream>>>(bufAct, wt3, h3b, 128, 64, 64);
    agg_lsm_kernel<<<AB, 256, 0, stream>>>(h3b, rowptr, erec, dinv, b3, out, N);
}